// Round 8
// baseline (294.348 us; speedup 1.0000x reference)
//
#include <hip/hip_runtime.h>

// Problem constants
#define B_Q   4096
#define E_DIM 512
#define N_C   2000
#define N_P   64000

// GEMM geometry: 256x256 tile, BK=64 (2 K-halves of 32), 8 waves (2M x 4N),
// double-buffered 128 KiB LDS, 16x16x32 MFMA.
// Round 8: 4-phase iteration (32 MFMA per barrier-pair) -- merges the MH0/MH1
// quadrant pair of the 8-phase schedule into one phase to amortize the
// ~650-cyc fixed per-phase overhead (2 barrier arrivals + wait scaffolding)
// over 2x the MFMA work.
#define BM 256
#define BN 256

typedef __bf16 bf16x8 __attribute__((ext_vector_type(8)));
typedef float  f32x4  __attribute__((ext_vector_type(4)));

__device__ __forceinline__ unsigned short f2bf(float f) {
  unsigned u = __builtin_bit_cast(unsigned, f);
  u += 0x7fffu + ((u >> 16) & 1u);
  return (unsigned short)(u >> 16);
}

__device__ __forceinline__ void async_ld16(const void* g, void* l) {
  __builtin_amdgcn_global_load_lds(
      (const __attribute__((address_space(1))) void*)g,
      (__attribute__((address_space(3))) void*)l,
      16, 0, 0);
}

// ---------------------------------------------------------------------------
// Row L2-normalize fp32 -> bf16 for BOTH inputs in one launch.
// ---------------------------------------------------------------------------
__global__ __launch_bounds__(128) void norm_rows_kernel(
    const float* __restrict__ w1, const float* __restrict__ data,
    unsigned short* __restrict__ wbf, unsigned short* __restrict__ dbf)
{
  int row = blockIdx.x;
  const float* in;
  unsigned short* outbf;
  if (row < N_P) { in = w1; outbf = wbf; }
  else           { in = data; outbf = dbf; row -= N_P; }
  const int tid = threadIdx.x;
  const float4 v = *(const float4*)(in + (size_t)row * E_DIM + tid * 4);
  float ss = v.x*v.x + v.y*v.y + v.z*v.z + v.w*v.w;
  #pragma unroll
  for (int s = 1; s < 64; s <<= 1) ss += __shfl_xor(ss, s);
  __shared__ float partial[2];
  if ((tid & 63) == 0) partial[tid >> 6] = ss;
  __syncthreads();
  const float tot = partial[0] + partial[1];
  const float inv = 1.0f / fmaxf(sqrtf(tot), 1e-12f);
  ushort4 o;
  o.x = f2bf(v.x * inv); o.y = f2bf(v.y * inv);
  o.z = f2bf(v.z * inv); o.w = f2bf(v.w * inv);
  *(ushort4*)(outbf + (size_t)row * E_DIM + tid * 4) = o;
}

// ---------------------------------------------------------------------------
// LDS: A[buf][h][256 rows][4 x 16B] @0, B same @65536; region = 16 KiB.
// Chunk swizzle: slot (row,cc) holds global chunk cc ^ ((row>>1)&3); stager
// pre-swizzles the GLOBAL source chunk, LDS dest stays linear.
//
// 4-phase iteration over k-tile pair (t on buf0, t+1 on buf1); each phase
// stages one (A+B) region pair (4 load-instr) and computes one (buf,h) of
// 32 MFMA:
//   P1 (0,h0): stage A+B(1,1,t+1)   P2 (0,h1): stage A+B(0,0,t+2)
//   P3 (1,h0): stage A+B(0,1,t+2)   P4 (1,h1): stage A+B(1,0,t+3)
// vmcnt ledger (4 instr/phase, uniform WAITV(8) leaves the newest 2 regions
// outstanding): the wait at phase p retires everything staged >= 2 phases
// back, which is exactly the region read at phase p+1's head.  End-barrier
// is load-bearing: stage(p) overwrites a region whose last reads drain at
// lgkmcnt(0) of p-1; SBAR_end(p-1) orders stage-issue after that drain.
// Drain iter (t=6): P1 stages (1,1,7) + WAITV(8); P2 WAITV(4); P3 WAITV(0).
// Prologue: 12 loads (regions 0.h0, 0.h1, 1.h0) + WAITV(8).
// ---------------------------------------------------------------------------
#define WAITV(N) asm volatile("s_waitcnt vmcnt(" #N ")" ::: "memory")
#define SBAR     asm volatile("s_barrier" ::: "memory")
#define NOPS     do {} while (0)

#define STAGE_A(BUF,H,KOFF) do { \
  async_ld16(gA + (KOFF)*64 + (H)*32,         smem + (BUF)*32768 + (H)*16384 + sdst); \
  async_ld16(gA + 65536 + (KOFF)*64 + (H)*32, smem + (BUF)*32768 + (H)*16384 + sdst + 8192); \
} while(0)

#define STAGE_B(BUF,H,KOFF) do { \
  async_ld16(gB + (KOFF)*64 + (H)*32,         smem + 65536 + (BUF)*32768 + (H)*16384 + sdst); \
  async_ld16(gB + 65536 + (KOFF)*64 + (H)*32, smem + 65536 + (BUF)*32768 + (H)*16384 + sdst + 8192); \
} while(0)

#define STAGE_AB(BUF,H,KOFF) do { STAGE_A(BUF,H,KOFF); STAGE_B(BUF,H,KOFF); } while(0)

// Head reads: all 12 fragments of (BUF,H) -- 8 A (m=0..7), 4 B (n=0..3).
#define RD(BUF,H) do { \
  fa0 = *(const bf16x8*)(pa + (BUF)*32768 + (H)*16384 + 0*1024); \
  fa1 = *(const bf16x8*)(pa + (BUF)*32768 + (H)*16384 + 1*1024); \
  fa2 = *(const bf16x8*)(pa + (BUF)*32768 + (H)*16384 + 2*1024); \
  fa3 = *(const bf16x8*)(pa + (BUF)*32768 + (H)*16384 + 3*1024); \
  fa4 = *(const bf16x8*)(pa + (BUF)*32768 + (H)*16384 + 4*1024); \
  fa5 = *(const bf16x8*)(pa + (BUF)*32768 + (H)*16384 + 5*1024); \
  fa6 = *(const bf16x8*)(pa + (BUF)*32768 + (H)*16384 + 6*1024); \
  fa7 = *(const bf16x8*)(pa + (BUF)*32768 + (H)*16384 + 7*1024); \
  fb0 = *(const bf16x8*)(pb + (BUF)*32768 + (H)*16384 + 0*1024); \
  fb1 = *(const bf16x8*)(pb + (BUF)*32768 + (H)*16384 + 1*1024); \
  fb2 = *(const bf16x8*)(pb + (BUF)*32768 + (H)*16384 + 2*1024); \
  fb3 = *(const bf16x8*)(pb + (BUF)*32768 + (H)*16384 + 3*1024); \
} while(0)

#define MMX(m,n) \
  acc[m][n] = __builtin_amdgcn_mfma_f32_16x16x32_bf16(fa##m, fb##n, acc[m][n], 0, 0, 0)

#define MFMA32 do { \
  MMX(0,0); MMX(0,1); MMX(0,2); MMX(0,3); \
  MMX(1,0); MMX(1,1); MMX(1,2); MMX(1,3); \
  MMX(2,0); MMX(2,1); MMX(2,2); MMX(2,3); \
  MMX(3,0); MMX(3,1); MMX(3,2); MMX(3,3); \
  MMX(4,0); MMX(4,1); MMX(4,2); MMX(4,3); \
  MMX(5,0); MMX(5,1); MMX(5,2); MMX(5,3); \
  MMX(6,0); MMX(6,1); MMX(6,2); MMX(6,3); \
  MMX(7,0); MMX(7,1); MMX(7,2); MMX(7,3); \
} while(0)

// Phase: stage next regions (loads issue earliest), head-read current frags,
// counted vmcnt wait (guards NEXT phase's reads), barrier, lgkm drain,
// 32 MFMA, end barrier.
#define PH4(BUF,H, STAGE, WAIT) do { \
  STAGE; \
  RD(BUF,H); \
  WAIT; \
  SBAR; \
  asm volatile("s_waitcnt lgkmcnt(0)" ::: "memory"); \
  __builtin_amdgcn_sched_barrier(0); \
  __builtin_amdgcn_s_setprio(1); \
  MFMA32; \
  __builtin_amdgcn_s_setprio(0); \
  SBAR; \
} while(0)

__global__ __launch_bounds__(512, 2) void gemm_max_kernel(
    const unsigned short* __restrict__ wbf,   // [64000][512] bf16, normalized
    const unsigned short* __restrict__ dbf,   // [4096][512]  bf16, normalized
    float* __restrict__ out)                  // [2000][4096]
{
  extern __shared__ char smem[];              // 131072 B

  const int tid  = threadIdx.x;
  const int lane = tid & 63;
  const int wid  = tid >> 6;      // 0..7
  const int wr   = wid >> 2;      // 0..1  (128 rows each)
  const int wc   = wid & 3;       // 0..3  (64 cols each)

  // XCD-aware swizzle: 4000 blocks, 8 XCDs, 500/chunk (bijective).
  const int bid  = blockIdx.x;
  const int wgid = (bid & 7) * 500 + (bid >> 3);
  const int rowb = wgid >> 4;     // 0..249
  const int colb = wgid & 15;     // 0..15
  const int rowBase = rowb * BM;
  const int colBase = colb * BN;

  // Staging: region = 256 rows x 32 shorts = 1024 x 16B chunks; thread t
  // handles chunks t (rows 0-127) and t+512 (rows 128-255).
  const int srow = tid >> 2;
  const int gch  = (tid & 3) ^ ((tid >> 3) & 3);   // pre-swizzled global chunk
  const unsigned short* gA = wbf + (size_t)(rowBase + srow) * E_DIM + gch * 8;
  const unsigned short* gB = dbf + (size_t)(colBase + srow) * E_DIM + gch * 8;
  const int sdst = tid * 16;      // linear LDS dest

  // Fragment read bases (swizzled chunk) -- identical to round 2 (0 conflicts)
  const int r   = lane & 15;
  const int kg  = lane >> 4;
  const int swz = (kg ^ ((r >> 1) & 3)) * 16;
  const char* pa = smem + (wr * 128 + r) * 64 + swz;
  const char* pb = smem + 65536 + (wc * 64 + r) * 64 + swz;

  f32x4 acc[8][4];
  #pragma unroll
  for (int m = 0; m < 8; ++m)
    #pragma unroll
    for (int n = 0; n < 4; ++n)
      acc[m][n] = (f32x4){0.f, 0.f, 0.f, 0.f};

  bf16x8 fa0, fa1, fa2, fa3, fa4, fa5, fa6, fa7;
  bf16x8 fb0, fb1, fb2, fb3;

  // Prologue: 12 loads (regions 0.h0, 0.h1, 1.h0), oldest 4 needed first.
  STAGE_AB(0,0,0);
  STAGE_AB(0,1,0);
  STAGE_AB(1,0,1);
  WAITV(8);
  SBAR;

  #pragma unroll 1
  for (int kt = 0; kt < 6; kt += 2) {
    PH4(0,0, STAGE_AB(1,1,kt+1), WAITV(8));
    PH4(0,1, STAGE_AB(0,0,kt+2), WAITV(8));
    PH4(1,0, STAGE_AB(0,1,kt+2), WAITV(8));
    PH4(1,1, STAGE_AB(1,0,kt+3), WAITV(8));
  }
  // Drain iteration (kt=6, tiles 6/7): only (1,1,7) left to stage.
  PH4(0,0, STAGE_AB(1,1,7), WAITV(8));
  PH4(0,1, NOPS,            WAITV(4));
  PH4(1,0, NOPS,            WAITV(0));
  PH4(1,1, NOPS,            NOPS);

  // Epilogue: per-class max (class = 32 rows = m-pair).  Wave row =
  // wr*128 + m*16 + kg*4 + j; reduce m-pair x j, then across kg (lanes).
  const int classBase = rowb * 8 + wr * 4;
  #pragma unroll
  for (int q = 0; q < 4; ++q) {
    #pragma unroll
    for (int n = 0; n < 4; ++n) {
      float pm = -3.4e38f;
      #pragma unroll
      for (int j = 0; j < 4; ++j)
        pm = fmaxf(pm, fmaxf(acc[2*q][n][j], acc[2*q+1][n][j]));
      pm = fmaxf(pm, __shfl_xor(pm, 16));
      pm = fmaxf(pm, __shfl_xor(pm, 32));
      if (lane < 16)
        out[(size_t)(classBase + q) * B_Q + colBase + wc * 64 + n * 16 + r] = pm;
    }
  }
}

// ---------------------------------------------------------------------------
extern "C" void kernel_launch(void* const* d_in, const int* in_sizes, int n_in,
                              void* d_out, int out_size, void* d_ws, size_t ws_size,
                              hipStream_t stream) {
  const float* data = (const float*)d_in[0];   // [4096][512]
  const float* w1   = (const float*)d_in[1];   // [64000][512]
  float* out = (float*)d_out;                  // [2000][4096]

  unsigned short* wbf = (unsigned short*)d_ws;
  unsigned short* dbf = wbf + (size_t)N_P * E_DIM;

  (void)hipFuncSetAttribute((const void*)gemm_max_kernel,
      hipFuncAttributeMaxDynamicSharedMemorySize, 131072);

  norm_rows_kernel<<<N_P + B_Q, 128, 0, stream>>>(w1, data, wbf, dbf);
  gemm_max_kernel<<<4000, 512, 131072, stream>>>(wbf, dbf, out);
}

// Round 9
// 282.077 us; speedup vs baseline: 1.0435x; 1.0435x over previous
//
#include <hip/hip_runtime.h>

// Problem constants
#define B_Q   4096
#define E_DIM 512
#define N_C   2000
#define N_P   64000

// GEMM geometry: 256x256 tile, BK=64 (2 K-halves of 32), 8 waves (2M x 4N),
// 8-phase schedule, double-buffered 128 KiB LDS, 16x16x32 MFMA.
// Round 9: round-7 tail-read fragment double-buffering + sched_group_barrier
// 1:1 MFMA/DS_READ interleave (T19/CK pattern) so the LDS-read burst of phase
// p+1 executes concurrently with phase p's MFMA burst instead of alternating.
#define BM 256
#define BN 256

typedef __bf16 bf16x8 __attribute__((ext_vector_type(8)));
typedef float  f32x4  __attribute__((ext_vector_type(4)));

__device__ __forceinline__ unsigned short f2bf(float f) {
  unsigned u = __builtin_bit_cast(unsigned, f);
  u += 0x7fffu + ((u >> 16) & 1u);
  return (unsigned short)(u >> 16);
}

__device__ __forceinline__ void async_ld16(const void* g, void* l) {
  __builtin_amdgcn_global_load_lds(
      (const __attribute__((address_space(1))) void*)g,
      (__attribute__((address_space(3))) void*)l,
      16, 0, 0);
}

// ---------------------------------------------------------------------------
// Row L2-normalize fp32 -> bf16 for BOTH inputs in one launch.
// ---------------------------------------------------------------------------
__global__ __launch_bounds__(128) void norm_rows_kernel(
    const float* __restrict__ w1, const float* __restrict__ data,
    unsigned short* __restrict__ wbf, unsigned short* __restrict__ dbf)
{
  int row = blockIdx.x;
  const float* in;
  unsigned short* outbf;
  if (row < N_P) { in = w1; outbf = wbf; }
  else           { in = data; outbf = dbf; row -= N_P; }
  const int tid = threadIdx.x;
  const float4 v = *(const float4*)(in + (size_t)row * E_DIM + tid * 4);
  float ss = v.x*v.x + v.y*v.y + v.z*v.z + v.w*v.w;
  #pragma unroll
  for (int s = 1; s < 64; s <<= 1) ss += __shfl_xor(ss, s);
  __shared__ float partial[2];
  if ((tid & 63) == 0) partial[tid >> 6] = ss;
  __syncthreads();
  const float tot = partial[0] + partial[1];
  const float inv = 1.0f / fmaxf(sqrtf(tot), 1e-12f);
  ushort4 o;
  o.x = f2bf(v.x * inv); o.y = f2bf(v.y * inv);
  o.z = f2bf(v.z * inv); o.w = f2bf(v.w * inv);
  *(ushort4*)(outbf + (size_t)row * E_DIM + tid * 4) = o;
}

// ---------------------------------------------------------------------------
// LDS: A[buf][h][256 rows][4 x 16B] @0, B same @65536; region = 16 KiB.
// Chunk swizzle: slot (row,cc) holds global chunk cc ^ ((row>>1)&3); stager
// pre-swizzles the GLOBAL source chunk, LDS dest stays linear.
// Staging ledger (verified rounds 2/7): per ii-block (k-tile k on buf0
// ph1-4, k+1 on buf1 ph5-8):
//   p1 A(1,1,k+1)  p2 B(1,1,k+1)  p3 A(0,0,k+2)  p4 B(0,0,k+2)
//   p5 A(0,1,k+2)  p6 B(0,1,k+2)  p7 A(1,0,k+3)  p8 B(1,0,k+3)
// WAITV(8) after even-phase stage guarantees regions staged >=4 phases back
// have landed.  Tail-read coverage (reads of phase p+1 issued inside p):
//   p1 tail (0,0) staged prev p3/p4 -> landed by prev-p8 WAITV(8)
//   p2 tail (0,1) staged prev p5/p6 -> landed by p2 WAITV(8)
//   p4 tail (1,0) staged prev p7/p8 -> landed by p4 WAITV(8)
//   p6 tail (1,1) staged cur  p1/p2 -> landed by p6 WAITV(8)
//   p8 tail (0,0) staged cur  p3/p4 -> landed by p8 WAITV(8)
// LDS WAR: every phase drains lgkm before MFMA + trailing barrier, so a
// region's reads complete >=1 phase before it is restaged.
// ---------------------------------------------------------------------------
#define WAITV(N) asm volatile("s_waitcnt vmcnt(" #N ")" ::: "memory")
#define SBAR     asm volatile("s_barrier" ::: "memory")
#define NOPS     do {} while (0)

#define STAGE_A(BUF,H,KOFF) do { \
  async_ld16(gA + (KOFF)*64 + (H)*32,         smem + (BUF)*32768 + (H)*16384 + sdst); \
  async_ld16(gA + 65536 + (KOFF)*64 + (H)*32, smem + (BUF)*32768 + (H)*16384 + sdst + 8192); \
} while(0)

#define STAGE_B(BUF,H,KOFF) do { \
  async_ld16(gB + (KOFF)*64 + (H)*32,         smem + 65536 + (BUF)*32768 + (H)*16384 + sdst); \
  async_ld16(gB + 65536 + (KOFF)*64 + (H)*32, smem + 65536 + (BUF)*32768 + (H)*16384 + sdst + 8192); \
} while(0)

// Fragment-register double buffering: A sets alternate every phase,
// B sets alternate every 2 phases (B frags serve an MH0/MH1 phase pair).
#define RDA(S,BUF,H,MH) do { \
  a##S##_0 = *(const bf16x8*)(pa + (BUF)*32768 + (H)*16384 + ((MH)*4+0)*1024); \
  a##S##_1 = *(const bf16x8*)(pa + (BUF)*32768 + (H)*16384 + ((MH)*4+1)*1024); \
  a##S##_2 = *(const bf16x8*)(pa + (BUF)*32768 + (H)*16384 + ((MH)*4+2)*1024); \
  a##S##_3 = *(const bf16x8*)(pa + (BUF)*32768 + (H)*16384 + ((MH)*4+3)*1024); \
} while(0)

#define RDB(S,BUF,H) do { \
  b##S##_0 = *(const bf16x8*)(pb + (BUF)*32768 + (H)*16384 +    0); \
  b##S##_1 = *(const bf16x8*)(pb + (BUF)*32768 + (H)*16384 + 1024); \
  b##S##_2 = *(const bf16x8*)(pb + (BUF)*32768 + (H)*16384 + 2048); \
  b##S##_3 = *(const bf16x8*)(pb + (BUF)*32768 + (H)*16384 + 3072); \
} while(0)

#define MM(AS,BS,MH,m,n) \
  acc[(MH)*4+m][n] = __builtin_amdgcn_mfma_f32_16x16x32_bf16( \
      a##AS##_##m, b##BS##_##n, acc[(MH)*4+m][n], 0, 0, 0)

#define MFMA16(AS,BS,MH) do { \
  MM(AS,BS,MH,0,0); MM(AS,BS,MH,0,1); MM(AS,BS,MH,0,2); MM(AS,BS,MH,0,3); \
  MM(AS,BS,MH,1,0); MM(AS,BS,MH,1,1); MM(AS,BS,MH,1,2); MM(AS,BS,MH,1,3); \
  MM(AS,BS,MH,2,0); MM(AS,BS,MH,2,1); MM(AS,BS,MH,2,2); MM(AS,BS,MH,2,3); \
  MM(AS,BS,MH,3,0); MM(AS,BS,MH,3,1); MM(AS,BS,MH,3,2); MM(AS,BS,MH,3,3); \
} while(0)

// sched_group_barrier interleave patterns (LLVM masks: MFMA=0x8, DS_READ=0x100).
#define SGB(M,N) __builtin_amdgcn_sched_group_barrier(M, N, 0)
// 4 tail reads (A-phases): {MFMA x2, DS_READ x1} x4, then MFMA x8.
#define ILV4 do { \
  SGB(0x8,2); SGB(0x100,1); SGB(0x8,2); SGB(0x100,1); \
  SGB(0x8,2); SGB(0x100,1); SGB(0x8,2); SGB(0x100,1); \
  SGB(0x8,8); \
} while(0)
// 8 tail reads (B-phases): {MFMA x1, DS_READ x1} x8, then MFMA x8.
#define ILV8 do { \
  SGB(0x8,1); SGB(0x100,1); SGB(0x8,1); SGB(0x100,1); \
  SGB(0x8,1); SGB(0x100,1); SGB(0x8,1); SGB(0x100,1); \
  SGB(0x8,1); SGB(0x100,1); SGB(0x8,1); SGB(0x100,1); \
  SGB(0x8,1); SGB(0x100,1); SGB(0x8,1); SGB(0x100,1); \
  SGB(0x8,8); \
} while(0)

// Phase: stage, counted vmcnt wait, barrier, lgkm drain (covers last phase's
// tail reads), MFMA on current frag sets interleaved (via ILV) with the tail
// reads of next phase's fragments, end barrier.
#define PHX(AS,BS,MH, STAGE, WAIT, TAIL, ILV) do { \
  STAGE; \
  WAIT; \
  SBAR; \
  asm volatile("s_waitcnt lgkmcnt(0)" ::: "memory"); \
  __builtin_amdgcn_sched_barrier(0); \
  __builtin_amdgcn_s_setprio(1); \
  MFMA16(AS,BS,MH); \
  TAIL; \
  ILV; \
  __builtin_amdgcn_s_setprio(0); \
  SBAR; \
} while(0)

// ii-block: phases (buf,h,MH) = (0,0,0)(0,0,1)(0,1,0)(0,1,1)(1,0,0)(1,0,1)
// (1,1,0)(1,1,1); A-set = phase parity, B-set toggles each even-phase tail.
#define IIBLK(K1,K2,K3) do { \
  PHX(0,0,0, STAGE_A(1,1,K1), NOPS,     RDA(1,0,0,1),             ILV4); \
  PHX(1,0,1, STAGE_B(1,1,K1), WAITV(8), RDA(0,0,1,0); RDB(1,0,1), ILV8); \
  PHX(0,1,0, STAGE_A(0,0,K2), NOPS,     RDA(1,0,1,1),             ILV4); \
  PHX(1,1,1, STAGE_B(0,0,K2), WAITV(8), RDA(0,1,0,0); RDB(0,1,0), ILV8); \
  PHX(0,0,0, STAGE_A(0,1,K2), NOPS,     RDA(1,1,0,1),             ILV4); \
  PHX(1,0,1, STAGE_B(0,1,K2), WAITV(8), RDA(0,1,1,0); RDB(1,1,1), ILV8); \
  PHX(0,1,0, STAGE_A(1,0,K3), NOPS,     RDA(1,1,1,1),             ILV4); \
  PHX(1,1,1, STAGE_B(1,0,K3), WAITV(8), RDA(0,0,0,0); RDB(0,0,0), ILV8); \
} while(0)

__global__ __launch_bounds__(512, 2) void gemm_max_kernel(
    const unsigned short* __restrict__ wbf,   // [64000][512] bf16, normalized
    const unsigned short* __restrict__ dbf,   // [4096][512]  bf16, normalized
    float* __restrict__ out)                  // [2000][4096]
{
  extern __shared__ char smem[];              // 131072 B

  const int tid  = threadIdx.x;
  const int lane = tid & 63;
  const int wid  = tid >> 6;      // 0..7
  const int wr   = wid >> 2;      // 0..1  (128 rows each)
  const int wc   = wid & 3;       // 0..3  (64 cols each)

  // XCD-aware swizzle: 4000 blocks, 8 XCDs, 500/chunk (bijective).
  const int bid  = blockIdx.x;
  const int wgid = (bid & 7) * 500 + (bid >> 3);
  const int rowb = wgid >> 4;     // 0..249
  const int colb = wgid & 15;     // 0..15
  const int rowBase = rowb * BM;
  const int colBase = colb * BN;

  // Staging: region = 256 rows x 32 shorts = 1024 x 16B chunks; thread t
  // handles chunks t (rows 0-127) and t+512 (rows 128-255).
  const int srow = tid >> 2;
  const int gch  = (tid & 3) ^ ((tid >> 3) & 3);   // pre-swizzled global chunk
  const unsigned short* gA = wbf + (size_t)(rowBase + srow) * E_DIM + gch * 8;
  const unsigned short* gB = dbf + (size_t)(colBase + srow) * E_DIM + gch * 8;
  const int sdst = tid * 16;      // linear LDS dest

  // Fragment read bases (swizzled chunk) -- identical to round 2 (0 conflicts)
  const int r   = lane & 15;
  const int kg  = lane >> 4;
  const int swz = (kg ^ ((r >> 1) & 3)) * 16;
  const char* pa = smem + (wr * 128 + r) * 64 + swz;
  const char* pb = smem + 65536 + (wc * 64 + r) * 64 + swz;

  f32x4 acc[8][4];
  #pragma unroll
  for (int m = 0; m < 8; ++m)
    #pragma unroll
    for (int n = 0; n < 4; ++n)
      acc[m][n] = (f32x4){0.f, 0.f, 0.f, 0.f};

  bf16x8 a0_0, a0_1, a0_2, a0_3, a1_0, a1_1, a1_2, a1_3;
  bf16x8 b0_0, b0_1, b0_2, b0_3, b1_0, b1_1, b1_2, b1_3;

  // Prologue: 12 loads (regions 0.h0, 0.h1, 1.h0), oldest 4 needed first;
  // then pre-read phase-1's fragments into set 0.
  STAGE_A(0,0,0); STAGE_B(0,0,0);
  STAGE_A(0,1,0); STAGE_B(0,1,0);
  STAGE_A(1,0,1); STAGE_B(1,0,1);
  WAITV(8);
  SBAR;
  RDA(0,0,0,0);
  RDB(0,0,0);

  #pragma unroll 1
  for (int kt = 0; kt < 6; kt += 2) {
    IIBLK(kt+1, kt+2, kt+3);
  }
  // Drain ii-block (kt=6): only tile7.h1 left to stage; waits 8/4/0.
  PHX(0,0,0, STAGE_A(1,1,7), NOPS,     RDA(1,0,0,1),             ILV4);
  PHX(1,0,1, STAGE_B(1,1,7), WAITV(8), RDA(0,0,1,0); RDB(1,0,1), ILV8);
  PHX(0,1,0, NOPS,           NOPS,     RDA(1,0,1,1),             ILV4);
  PHX(1,1,1, NOPS,           WAITV(4), RDA(0,1,0,0); RDB(0,1,0), ILV8);
  PHX(0,0,0, NOPS,           NOPS,     RDA(1,1,0,1),             ILV4);
  PHX(1,0,1, NOPS,           WAITV(0), RDA(0,1,1,0); RDB(1,1,1), ILV8);
  PHX(0,1,0, NOPS,           NOPS,     RDA(1,1,1,1),             ILV4);
  PHX(1,1,1, NOPS,           NOPS,     NOPS,                     NOPS);

  // Epilogue: per-class max (class = 32 rows = m-pair).  Wave row =
  // wr*128 + m*16 + kg*4 + j; reduce m-pair x j, then across kg (lanes).
  const int classBase = rowb * 8 + wr * 4;
  #pragma unroll
  for (int q = 0; q < 4; ++q) {
    #pragma unroll
    for (int n = 0; n < 4; ++n) {
      float pm = -3.4e38f;
      #pragma unroll
      for (int j = 0; j < 4; ++j)
        pm = fmaxf(pm, fmaxf(acc[2*q][n][j], acc[2*q+1][n][j]));
      pm = fmaxf(pm, __shfl_xor(pm, 16));
      pm = fmaxf(pm, __shfl_xor(pm, 32));
      if (lane < 16)
        out[(size_t)(classBase + q) * B_Q + colBase + wc * 64 + n * 16 + r] = pm;
    }
  }
}

// ---------------------------------------------------------------------------
extern "C" void kernel_launch(void* const* d_in, const int* in_sizes, int n_in,
                              void* d_out, int out_size, void* d_ws, size_t ws_size,
                              hipStream_t stream) {
  const float* data = (const float*)d_in[0];   // [4096][512]
  const float* w1   = (const float*)d_in[1];   // [64000][512]
  float* out = (float*)d_out;                  // [2000][4096]

  unsigned short* wbf = (unsigned short*)d_ws;
  unsigned short* dbf = wbf + (size_t)N_P * E_DIM;

  (void)hipFuncSetAttribute((const void*)gemm_max_kernel,
      hipFuncAttributeMaxDynamicSharedMemorySize, 131072);

  norm_rows_kernel<<<N_P + B_Q, 128, 0, stream>>>(w1, data, wbf, dbf);
  gemm_max_kernel<<<4000, 512, 131072, stream>>>(wbf, dbf, out);
}

// Round 10
// 280.736 us; speedup vs baseline: 1.0485x; 1.0048x over previous
//
#include <hip/hip_runtime.h>

// Problem constants
#define B_Q   4096
#define E_DIM 512
#define N_C   2000
#define N_P   64000

// GEMM geometry: 256x256 tile, BK=64 (2 K-halves of 32), 8 waves (2M x 4N),
// 8-phase schedule, double-buffered 128 KiB LDS, 16x16x32 MFMA.
// Round 10: LOAD-BALANCED tail reads -- every phase reads exactly 6 frags
// (4 A + 2 B) instead of alternating 4/12.  B-set reads split across the two
// phases preceding first use; vmcnt waits shift to WAITV(6) at ODD phases.
#define BM 256
#define BN 256

typedef __bf16 bf16x8 __attribute__((ext_vector_type(8)));
typedef float  f32x4  __attribute__((ext_vector_type(4)));

__device__ __forceinline__ unsigned short f2bf(float f) {
  unsigned u = __builtin_bit_cast(unsigned, f);
  u += 0x7fffu + ((u >> 16) & 1u);
  return (unsigned short)(u >> 16);
}

__device__ __forceinline__ void async_ld16(const void* g, void* l) {
  __builtin_amdgcn_global_load_lds(
      (const __attribute__((address_space(1))) void*)g,
      (__attribute__((address_space(3))) void*)l,
      16, 0, 0);
}

// ---------------------------------------------------------------------------
// Row L2-normalize fp32 -> bf16 for BOTH inputs in one launch.
// ---------------------------------------------------------------------------
__global__ __launch_bounds__(128) void norm_rows_kernel(
    const float* __restrict__ w1, const float* __restrict__ data,
    unsigned short* __restrict__ wbf, unsigned short* __restrict__ dbf)
{
  int row = blockIdx.x;
  const float* in;
  unsigned short* outbf;
  if (row < N_P) { in = w1; outbf = wbf; }
  else           { in = data; outbf = dbf; row -= N_P; }
  const int tid = threadIdx.x;
  const float4 v = *(const float4*)(in + (size_t)row * E_DIM + tid * 4);
  float ss = v.x*v.x + v.y*v.y + v.z*v.z + v.w*v.w;
  #pragma unroll
  for (int s = 1; s < 64; s <<= 1) ss += __shfl_xor(ss, s);
  __shared__ float partial[2];
  if ((tid & 63) == 0) partial[tid >> 6] = ss;
  __syncthreads();
  const float tot = partial[0] + partial[1];
  const float inv = 1.0f / fmaxf(sqrtf(tot), 1e-12f);
  ushort4 o;
  o.x = f2bf(v.x * inv); o.y = f2bf(v.y * inv);
  o.z = f2bf(v.z * inv); o.w = f2bf(v.w * inv);
  *(ushort4*)(outbf + (size_t)row * E_DIM + tid * 4) = o;
}

// ---------------------------------------------------------------------------
// LDS: A[buf][h][256 rows][4 x 16B] @0, B same @65536; region = 16 KiB.
// Chunk swizzle: slot (row,cc) holds global chunk cc ^ ((row>>1)&3); stager
// pre-swizzles the GLOBAL source chunk, LDS dest stays linear.
// Staging (same content as rounds 2-9): p1 A(1,1,k+1) p2 B(1,1,k+1)
//   p3 A(0,0,k+2) p4 B(0,0,k+2) p5 A(0,1,k+2) p6 B(0,1,k+2)
//   p7 A(1,0,k+3) p8 B(1,0,k+3)
// Balanced tail-read schedule (reads for later phases, 6 frags each):
//   p1: a1<-A(0,0)[1], b1f01<-B(0,1)   p2: a0<-A(0,1)[0], b1f23<-B(0,1)
//   p3: a1<-A(0,1)[1], b0f01<-B(1,0)   p4: a0<-A(1,0)[0], b0f23<-B(1,0)
//   p5: a1<-A(1,0)[1], b1f01<-B(1,1)   p6: a0<-A(1,1)[0], b1f23<-B(1,1)
//   p7: a1<-A(1,1)[1], b0f01<-B(0,0)'  p8: a0<-A(0,0)[0]', b0f23<-B(0,0)'
// vmcnt ledger: WAITV(6) at ODD phases (after odd stage, outstanding=10;
// retires the region PAIR staged 4 phases earlier = exactly what this tail
// reads): p1 retires A/B(0,1); p3 retires A/B(1,0); p5 retires A/B(1,1);
// p7 retires A/B(0,0)'.  Even phases need no wait (their tails read regions
// already retired at the preceding odd wait).  WAR: reads of a region drain
// (lgkmcnt 0) >=1 phase before its restage.  Drain: waits 6/4/0 at d1/d3/d5.
// ---------------------------------------------------------------------------
#define WAITV(N) asm volatile("s_waitcnt vmcnt(" #N ")" ::: "memory")
#define SBAR     asm volatile("s_barrier" ::: "memory")
#define NOPS     do {} while (0)

#define STAGE_A(BUF,H,KOFF) do { \
  async_ld16(gA + (KOFF)*64 + (H)*32,         smem + (BUF)*32768 + (H)*16384 + sdst); \
  async_ld16(gA + 65536 + (KOFF)*64 + (H)*32, smem + (BUF)*32768 + (H)*16384 + sdst + 8192); \
} while(0)

#define STAGE_B(BUF,H,KOFF) do { \
  async_ld16(gB + (KOFF)*64 + (H)*32,         smem + 65536 + (BUF)*32768 + (H)*16384 + sdst); \
  async_ld16(gB + 65536 + (KOFF)*64 + (H)*32, smem + 65536 + (BUF)*32768 + (H)*16384 + sdst + 8192); \
} while(0)

// Fragment-register double buffering: A sets alternate every phase,
// B sets alternate every 2 phases; B reads split 2+2 over two tails.
#define RDA(S,BUF,H,MH) do { \
  a##S##_0 = *(const bf16x8*)(pa + (BUF)*32768 + (H)*16384 + ((MH)*4+0)*1024); \
  a##S##_1 = *(const bf16x8*)(pa + (BUF)*32768 + (H)*16384 + ((MH)*4+1)*1024); \
  a##S##_2 = *(const bf16x8*)(pa + (BUF)*32768 + (H)*16384 + ((MH)*4+2)*1024); \
  a##S##_3 = *(const bf16x8*)(pa + (BUF)*32768 + (H)*16384 + ((MH)*4+3)*1024); \
} while(0)

#define RDB01(S,BUF,H) do { \
  b##S##_0 = *(const bf16x8*)(pb + (BUF)*32768 + (H)*16384 +    0); \
  b##S##_1 = *(const bf16x8*)(pb + (BUF)*32768 + (H)*16384 + 1024); \
} while(0)

#define RDB23(S,BUF,H) do { \
  b##S##_2 = *(const bf16x8*)(pb + (BUF)*32768 + (H)*16384 + 2048); \
  b##S##_3 = *(const bf16x8*)(pb + (BUF)*32768 + (H)*16384 + 3072); \
} while(0)

#define MM(AS,BS,MH,m,n) \
  acc[(MH)*4+m][n] = __builtin_amdgcn_mfma_f32_16x16x32_bf16( \
      a##AS##_##m, b##BS##_##n, acc[(MH)*4+m][n], 0, 0, 0)

#define MFMA16(AS,BS,MH) do { \
  MM(AS,BS,MH,0,0); MM(AS,BS,MH,0,1); MM(AS,BS,MH,0,2); MM(AS,BS,MH,0,3); \
  MM(AS,BS,MH,1,0); MM(AS,BS,MH,1,1); MM(AS,BS,MH,1,2); MM(AS,BS,MH,1,3); \
  MM(AS,BS,MH,2,0); MM(AS,BS,MH,2,1); MM(AS,BS,MH,2,2); MM(AS,BS,MH,2,3); \
  MM(AS,BS,MH,3,0); MM(AS,BS,MH,3,1); MM(AS,BS,MH,3,2); MM(AS,BS,MH,3,3); \
} while(0)

// sched_group_barrier interleave (LLVM masks: MFMA=0x8, DS_READ=0x100).
#define SGB(M,N) __builtin_amdgcn_sched_group_barrier(M, N, 0)
// 6 tail reads: {MFMA x2, DS_READ x1} x6, then MFMA x4.
#define ILV6 do { \
  SGB(0x8,2); SGB(0x100,1); SGB(0x8,2); SGB(0x100,1); \
  SGB(0x8,2); SGB(0x100,1); SGB(0x8,2); SGB(0x100,1); \
  SGB(0x8,2); SGB(0x100,1); SGB(0x8,2); SGB(0x100,1); \
  SGB(0x8,4); \
} while(0)
// 4 tail reads: {MFMA x2, DS_READ x1} x4, then MFMA x8.
#define ILV4 do { \
  SGB(0x8,2); SGB(0x100,1); SGB(0x8,2); SGB(0x100,1); \
  SGB(0x8,2); SGB(0x100,1); SGB(0x8,2); SGB(0x100,1); \
  SGB(0x8,8); \
} while(0)

// Phase: stage, counted vmcnt wait, barrier, lgkm drain (covers last phase's
// tail reads), MFMA interleaved with next-phase tail reads, end barrier.
#define PHX(AS,BS,MH, STAGE, WAIT, TAIL, ILV) do { \
  STAGE; \
  WAIT; \
  SBAR; \
  asm volatile("s_waitcnt lgkmcnt(0)" ::: "memory"); \
  __builtin_amdgcn_sched_barrier(0); \
  __builtin_amdgcn_s_setprio(1); \
  MFMA16(AS,BS,MH); \
  TAIL; \
  ILV; \
  __builtin_amdgcn_s_setprio(0); \
  SBAR; \
} while(0)

// ii-block: phases (AS,BS,MH); balanced tails per the header table.
#define IIBLK(K1,K2,K3) do { \
  PHX(0,0,0, STAGE_A(1,1,K1), WAITV(6), RDA(1,0,0,1); RDB01(1,0,1), ILV6); \
  PHX(1,0,1, STAGE_B(1,1,K1), NOPS,     RDA(0,0,1,0); RDB23(1,0,1), ILV6); \
  PHX(0,1,0, STAGE_A(0,0,K2), WAITV(6), RDA(1,0,1,1); RDB01(0,1,0), ILV6); \
  PHX(1,1,1, STAGE_B(0,0,K2), NOPS,     RDA(0,1,0,0); RDB23(0,1,0), ILV6); \
  PHX(0,0,0, STAGE_A(0,1,K2), WAITV(6), RDA(1,1,0,1); RDB01(1,1,1), ILV6); \
  PHX(1,0,1, STAGE_B(0,1,K2), NOPS,     RDA(0,1,1,0); RDB23(1,1,1), ILV6); \
  PHX(0,1,0, STAGE_A(1,0,K3), WAITV(6), RDA(1,1,1,1); RDB01(0,0,0), ILV6); \
  PHX(1,1,1, STAGE_B(1,0,K3), NOPS,     RDA(0,0,0,0); RDB23(0,0,0), ILV6); \
} while(0)

__global__ __launch_bounds__(512, 2) void gemm_max_kernel(
    const unsigned short* __restrict__ wbf,   // [64000][512] bf16, normalized
    const unsigned short* __restrict__ dbf,   // [4096][512]  bf16, normalized
    float* __restrict__ out)                  // [2000][4096]
{
  extern __shared__ char smem[];              // 131072 B

  const int tid  = threadIdx.x;
  const int lane = tid & 63;
  const int wid  = tid >> 6;      // 0..7
  const int wr   = wid >> 2;      // 0..1  (128 rows each)
  const int wc   = wid & 3;       // 0..3  (64 cols each)

  // XCD-aware swizzle: 4000 blocks, 8 XCDs, 500/chunk (bijective).
  const int bid  = blockIdx.x;
  const int wgid = (bid & 7) * 500 + (bid >> 3);
  const int rowb = wgid >> 4;     // 0..249
  const int colb = wgid & 15;     // 0..15
  const int rowBase = rowb * BM;
  const int colBase = colb * BN;

  // Staging: region = 256 rows x 32 shorts = 1024 x 16B chunks; thread t
  // handles chunks t (rows 0-127) and t+512 (rows 128-255).
  const int srow = tid >> 2;
  const int gch  = (tid & 3) ^ ((tid >> 3) & 3);   // pre-swizzled global chunk
  const unsigned short* gA = wbf + (size_t)(rowBase + srow) * E_DIM + gch * 8;
  const unsigned short* gB = dbf + (size_t)(colBase + srow) * E_DIM + gch * 8;
  const int sdst = tid * 16;      // linear LDS dest

  // Fragment read bases (swizzled chunk) -- identical to round 2 (0 conflicts)
  const int r   = lane & 15;
  const int kg  = lane >> 4;
  const int swz = (kg ^ ((r >> 1) & 3)) * 16;
  const char* pa = smem + (wr * 128 + r) * 64 + swz;
  const char* pb = smem + 65536 + (wc * 64 + r) * 64 + swz;

  f32x4 acc[8][4];
  #pragma unroll
  for (int m = 0; m < 8; ++m)
    #pragma unroll
    for (int n = 0; n < 4; ++n)
      acc[m][n] = (f32x4){0.f, 0.f, 0.f, 0.f};

  bf16x8 a0_0, a0_1, a0_2, a0_3, a1_0, a1_1, a1_2, a1_3;
  bf16x8 b0_0, b0_1, b0_2, b0_3, b1_0, b1_1, b1_2, b1_3;

  // Prologue: 12 loads (regions 0.h0, 0.h1, 1.h0), oldest 4 needed first;
  // then pre-read phase-1's fragments into sets 0.
  STAGE_A(0,0,0); STAGE_B(0,0,0);
  STAGE_A(0,1,0); STAGE_B(0,1,0);
  STAGE_A(1,0,1); STAGE_B(1,0,1);
  WAITV(8);
  SBAR;
  RDA(0,0,0,0);
  RDB01(0,0,0);
  RDB23(0,0,0);

  #pragma unroll 1
  for (int kt = 0; kt < 6; kt += 2) {
    IIBLK(kt+1, kt+2, kt+3);
  }
  // Drain ii-block (kt=6): only tile7.h1 left to stage; waits 6/4/0.
  PHX(0,0,0, STAGE_A(1,1,7), WAITV(6), RDA(1,0,0,1); RDB01(1,0,1), ILV6);
  PHX(1,0,1, STAGE_B(1,1,7), NOPS,     RDA(0,0,1,0); RDB23(1,0,1), ILV6);
  PHX(0,1,0, NOPS,           WAITV(4), RDA(1,0,1,1); RDB01(0,1,0), ILV6);
  PHX(1,1,1, NOPS,           NOPS,     RDA(0,1,0,0); RDB23(0,1,0), ILV6);
  PHX(0,0,0, NOPS,           WAITV(0), RDA(1,1,0,1); RDB01(1,1,1), ILV6);
  PHX(1,0,1, NOPS,           NOPS,     RDA(0,1,1,0); RDB23(1,1,1), ILV6);
  PHX(0,1,0, NOPS,           NOPS,     RDA(1,1,1,1),               ILV4);
  PHX(1,1,1, NOPS,           NOPS,     NOPS,                       NOPS);

  // Epilogue: per-class max (class = 32 rows = m-pair).  Wave row =
  // wr*128 + m*16 + kg*4 + j; reduce m-pair x j, then across kg (lanes).
  const int classBase = rowb * 8 + wr * 4;
  #pragma unroll
  for (int q = 0; q < 4; ++q) {
    #pragma unroll
    for (int n = 0; n < 4; ++n) {
      float pm = -3.4e38f;
      #pragma unroll
      for (int j = 0; j < 4; ++j)
        pm = fmaxf(pm, fmaxf(acc[2*q][n][j], acc[2*q+1][n][j]));
      pm = fmaxf(pm, __shfl_xor(pm, 16));
      pm = fmaxf(pm, __shfl_xor(pm, 32));
      if (lane < 16)
        out[(size_t)(classBase + q) * B_Q + colBase + wc * 64 + n * 16 + r] = pm;
    }
  }
}

// ---------------------------------------------------------------------------
extern "C" void kernel_launch(void* const* d_in, const int* in_sizes, int n_in,
                              void* d_out, int out_size, void* d_ws, size_t ws_size,
                              hipStream_t stream) {
  const float* data = (const float*)d_in[0];   // [4096][512]
  const float* w1   = (const float*)d_in[1];   // [64000][512]
  float* out = (float*)d_out;                  // [2000][4096]

  unsigned short* wbf = (unsigned short*)d_ws;
  unsigned short* dbf = wbf + (size_t)N_P * E_DIM;

  (void)hipFuncSetAttribute((const void*)gemm_max_kernel,
      hipFuncAttributeMaxDynamicSharedMemorySize, 131072);

  norm_rows_kernel<<<N_P + B_Q, 128, 0, stream>>>(w1, data, wbf, dbf);
  gemm_max_kernel<<<4000, 512, 131072, stream>>>(wbf, dbf, out);
}